// Round 6
// baseline (536.333 us; speedup 1.0000x reference)
//
#include <hip/hip_runtime.h>
#include <stdint.h>

#define Hh 128
#define Aa 16
#define Tt 4
#define K1 144
#define K1P 160     // transposed-weight row length (k 144..159 zeroed)
#define WG_LD  136  // pad: stride 272B -> bank advance 4 dw -> 2-way (free)

typedef float f32x4 __attribute__((ext_vector_type(4)));
typedef __bf16 bf16x8 __attribute__((ext_vector_type(8)));
typedef unsigned short u16x8 __attribute__((ext_vector_type(8)));
typedef unsigned short u16x4 __attribute__((ext_vector_type(4)));

static __device__ __forceinline__ unsigned short f2bf(float f) {
    unsigned u = __builtin_bit_cast(unsigned, f);
    u += 0x7fffu + ((u >> 16) & 1u);   // RNE
    return (unsigned short)(u >> 16);
}

static __device__ __forceinline__ float bf2f(unsigned short u) {
    return __builtin_bit_cast(float, (unsigned)u << 16);
}

static __device__ __forceinline__ bf16x8 pack8(const float* __restrict__ x) {
    f32x4 a = *(const f32x4*)x;
    f32x4 b = *(const f32x4*)(x + 4);
    u16x8 t;
    t[0] = f2bf(a[0]); t[1] = f2bf(a[1]); t[2] = f2bf(a[2]); t[3] = f2bf(a[3]);
    t[4] = f2bf(b[0]); t[5] = f2bf(b[1]); t[6] = f2bf(b[2]); t[7] = f2bf(b[3]);
    return __builtin_bit_cast(bf16x8, t);
}

static __device__ __forceinline__ bf16x8 zero_bf8() {
    u16x8 z = {0, 0, 0, 0, 0, 0, 0, 0};
    return __builtin_bit_cast(bf16x8, z);
}

// ============ fused bf16 pre-cast of h, w_ih, w_hh
__global__ void cast_all_kernel(
    const float* __restrict__ h, const float* __restrict__ wih, const float* __restrict__ whh,
    unsigned short* __restrict__ h_bf, unsigned short* __restrict__ wihb,
    unsigned short* __restrict__ whhb, int n0, int n1, int n2)
{
    int i = blockIdx.x * blockDim.x + threadIdx.x;
    if (i >= n2) return;
    const float* s; unsigned short* d; int off;
    if (i < n0)      { s = h;   d = h_bf; off = i; }
    else if (i < n1) { s = wih; d = wihb; off = i - n0; }
    else             { s = whh; d = whhb; off = i - n1; }
    f32x4 v = *(const f32x4*)(s + (size_t)off * 4);
    u16x4 o;
    o[0] = f2bf(v[0]); o[1] = f2bf(v[1]); o[2] = f2bf(v[2]); o[3] = f2bf(v[3]);
    *(u16x4*)(d + (size_t)off * 4) = o;
}

// ============ one-time transpose+cast: W1 [T][K1][H] f32 -> W1Tbf [T][H][K1P] bf16.
// k in [K1, K1P) zeroed (MUST be zero: garbage could be NaN, NaN*0=NaN in MFMA).
__global__ void w1t_kernel(const float* __restrict__ W1, unsigned short* __restrict__ W1Tbf) {
    __shared__ float tile[16][129];
    const int b = blockIdx.x;
    const int t = b / 10, kb = b % 10;
    const int k0 = kb * 16;
    const int tid = threadIdx.x;
    for (int e = tid; e < 16 * 128; e += 256) {
        int k = e >> 7, n = e & 127;
        tile[k][n] = (k0 + k < K1) ? W1[((size_t)t * K1 + k0 + k) * Hh + n] : 0.f;
    }
    __syncthreads();
    for (int e = tid; e < 128 * 16; e += 256) {
        int n = e >> 4, kk = e & 15;
        W1Tbf[((size_t)t * Hh + n) * K1P + k0 + kk] = f2bf(tile[kk][n]);
    }
}

// ============ one-time transpose+cast: W2 [T][H][H] f32 -> W2Tbf [T][n][k] bf16
__global__ void w2t_kernel(const float* __restrict__ W2, unsigned short* __restrict__ W2Tbf) {
    __shared__ float tile[16][129];
    const int b = blockIdx.x;
    const int t = b >> 3, kb = b & 7;
    const int k0 = kb * 16;
    const int tid = threadIdx.x;
    for (int e = tid; e < 16 * 128; e += 256) {
        int k = e >> 7, n = e & 127;
        tile[k][n] = W2[((size_t)t * Hh + k0 + k) * Hh + n];
    }
    __syncthreads();
    for (int e = tid; e < 128 * 16; e += 256) {
        int n = e >> 4, kk = e & 15;
        W2Tbf[((size_t)t * Hh + n) * Hh + k0 + kk] = f2bf(tile[kk][n]);
    }
}

// ============ bucketing by (type,dst) only: bins [0,4N)
__global__ void hist_kernel(const int* __restrict__ et, const int* __restrict__ eidx,
                            int E, int N, int* __restrict__ cnt, unsigned* __restrict__ rank) {
    for (int i = blockIdx.x * blockDim.x + threadIdx.x; i < E; i += gridDim.x * blockDim.x) {
        rank[i] = (unsigned)atomicAdd(&cnt[et[i] * N + eidx[E + i]], 1);
    }
}

// per-1024-chunk block sums
__global__ void scanA_kernel(const int* __restrict__ deg2, int nb, int* __restrict__ bsum) {
    __shared__ int red[256];
    const int t = threadIdx.x;
    const int i0 = blockIdx.x * 1024 + t * 4;
    int s = 0;
    #pragma unroll
    for (int j = 0; j < 4; j++) if (i0 + j < nb) s += deg2[i0 + j];
    red[t] = s; __syncthreads();
    for (int d = 128; d > 0; d >>= 1) {
        if (t < d) red[t] += red[t + d];
        __syncthreads();
    }
    if (t == 0) bsum[blockIdx.x] = red[0];
}

// single-block exclusive scan of block sums (nblocks <= 512); closes rowptr
__global__ void scanB_kernel(int* __restrict__ bsum, int nblocks,
                             int* __restrict__ rowptrD, int fourN, int E) {
    __shared__ int ts[512];
    const int t = threadIdx.x;
    int v = (t < nblocks) ? bsum[t] : 0;
    ts[t] = v; __syncthreads();
    for (int d = 1; d < 512; d <<= 1) {
        int x = (t >= d) ? ts[t - d] : 0;
        __syncthreads();
        ts[t] += x;
        __syncthreads();
    }
    if (t < nblocks) bsum[t] = ts[t] - v;
    if (t == 0) rowptrD[fourN] = E;
}

// per-chunk exclusive scan + global offset; rowptrD + bin starts in-place
__global__ void scanC_kernel(int* __restrict__ cur, int nb,
                             const int* __restrict__ bsum, int* __restrict__ rowptrD) {
    __shared__ int ts[256];
    const int t = threadIdx.x;
    const int i0 = blockIdx.x * 1024 + t * 4;
    int v[4];
    #pragma unroll
    for (int j = 0; j < 4; j++) v[j] = (i0 + j < nb) ? cur[i0 + j] : 0;
    int s = v[0] + v[1] + v[2] + v[3];
    ts[t] = s; __syncthreads();
    for (int d = 1; d < 256; d <<= 1) {
        int x = (t >= d) ? ts[t - d] : 0;
        __syncthreads();
        ts[t] += x;
        __syncthreads();
    }
    int run = bsum[blockIdx.x] + ts[t] - s;
    #pragma unroll
    for (int j = 0; j < 4; j++) {
        if (i0 + j < nb) {
            rowptrD[i0 + j] = run;
            cur[i0 + j] = run;
            run += v[j];
        }
    }
}

// atomic-free placement into dst-order: rec[posD] = (src, eidx)
__global__ void fill2_kernel(const int* __restrict__ et, const int* __restrict__ eidx,
                             int E, int N, const int* __restrict__ binstart,
                             const unsigned* __restrict__ rank, int2* __restrict__ rec) {
    for (int i = blockIdx.x * blockDim.x + threadIdx.x; i < E; i += gridDim.x * blockDim.x) {
        int posD = binstart[et[i] * N + eidx[E + i]] + (int)rank[i];
        rec[posD] = make_int2(eidx[i], i);
    }
}

// ---------------- layer 1, dst-order: iterate edges sequentially in (type,dst)
// position; GATHER h[src] (random reads, h_bf is L3-resident so HBM cost ~unique
// 12.8MB); write Yg SEQUENTIALLY (row = position) -> no scattered-write RFO
// amplification (rounds 0/2/5 all showed 4x WRITE blowup on scattered rows).
// W1 fragments read DIRECTLY from global W1Tbf (164KB, L2-resident): no LDS
// staging, no bank conflicts, no per-block staging overhead.
// acc[8][2] in AGPR; ks-loop kept rolled + sched_barrier fences to cap VGPR
// (round 5: unrolled epilogue pipelining inflated arch VGPR to 128 -> 192 total
// -> 1 blk/CU + spill).
__global__ __launch_bounds__(512) void l1_kernel(
    const unsigned short* __restrict__ h_bf, const int2* __restrict__ rec,
    const float* __restrict__ eattr, const unsigned short* __restrict__ W1Tbf,
    const float* __restrict__ b1, const int* __restrict__ rowptrD,
    unsigned short* __restrict__ Yg, int N)
{
    __shared__ float b1s[128];
    const int t = blockIdx.x & 3;
    const int lb = blockIdx.x >> 2;
    const int nbk = gridDim.x >> 2;
    const int tid = threadIdx.x;
    if (tid < 128) b1s[tid] = b1[t * Hh + tid];
    __syncthreads();

    const int tstart = rowptrD[t * N];
    const int tend = rowptrD[(t + 1) * N];
    const int cnt = tend - tstart;
    const int ntiles = (cnt + 255) >> 8;       // 256 edges per block-tile
    const int w = tid >> 6, lane = tid & 63;
    const int l15 = lane & 15, q = lane >> 4;
    const int tl = tend - 1;
    // per-lane W1 fragment base: row l15 of each 16-row mt block, cols q*8..
    const unsigned short* __restrict__ Wt =
        W1Tbf + (size_t)t * Hh * K1P + (size_t)l15 * K1P + q * 8;

    for (int tile = lb; tile < ntiles; tile += nbk) {
        __builtin_amdgcn_sched_barrier(0);
        const int p0 = tstart + tile * 256 + w * 32;
        const int pa = p0 + l15, pb = p0 + 16 + l15;
        const bool va = pa < tend, vb = pb < tend;
        const int2 ra = rec[min(pa, tl)];
        const int2 rb = rec[min(pb, tl)];
        const unsigned short* __restrict__ hA = h_bf + (size_t)ra.x * Hh;
        const unsigned short* __restrict__ hB = h_bf + (size_t)rb.x * Hh;

        f32x4 acc[8][2];
        #pragma unroll
        for (int mt = 0; mt < 8; mt++) {
            acc[mt][0] = (f32x4){0.f, 0.f, 0.f, 0.f};
            acc[mt][1] = (f32x4){0.f, 0.f, 0.f, 0.f};
        }

        #pragma unroll 1
        for (int ks = 0; ks < 4; ks++) {
            const int k0 = ks * 32;
            bf16x8 fb_a = __builtin_bit_cast(bf16x8, *(const u16x8*)(hA + k0 + q * 8));
            bf16x8 fb_b = __builtin_bit_cast(bf16x8, *(const u16x8*)(hB + k0 + q * 8));
            #pragma unroll
            for (int mt = 0; mt < 8; mt++) {
                bf16x8 fa = *(const bf16x8*)(Wt + (size_t)mt * 16 * K1P + k0);
                acc[mt][0] = __builtin_amdgcn_mfma_f32_16x16x32_bf16(fa, fb_a, acc[mt][0], 0, 0, 0);
                acc[mt][1] = __builtin_amdgcn_mfma_f32_16x16x32_bf16(fa, fb_b, acc[mt][1], 0, 0, 0);
            }
        }
        {   // ks=4 tail: edge_attr in k 128..143 (q<2), zeros in 144..159
            bf16x8 fb_a, fb_b;
            if (q < 2) {
                fb_a = pack8(eattr + (size_t)ra.y * Aa + q * 8);
                fb_b = pack8(eattr + (size_t)rb.y * Aa + q * 8);
            } else {
                fb_a = zero_bf8();
                fb_b = zero_bf8();
            }
            #pragma unroll
            for (int mt = 0; mt < 8; mt++) {
                bf16x8 fa = *(const bf16x8*)(Wt + (size_t)mt * 16 * K1P + 128);
                acc[mt][0] = __builtin_amdgcn_mfma_f32_16x16x32_bf16(fa, fb_a, acc[mt][0], 0, 0, 0);
                acc[mt][1] = __builtin_amdgcn_mfma_f32_16x16x32_bf16(fa, fb_b, acc[mt][1], 0, 0, 0);
            }
        }
        __builtin_amdgcn_sched_barrier(0);

        // epilogue: bias+relu+cvt, SEQUENTIAL rows (pa/pb are consecutive)
        #pragma unroll
        for (int g = 0; g < 2; g++) {
            if (g ? vb : va) {
                unsigned short* __restrict__ o = Yg + (size_t)(g ? pb : pa) * Hh + q * 4;
                #pragma unroll
                for (int mt = 0; mt < 8; mt++) {
                    f32x4 bias = *(const f32x4*)&b1s[mt * 16 + q * 4];
                    u16x4 y;
                    #pragma unroll
                    for (int i = 0; i < 4; i++) {
                        float v = acc[mt][g][i] + bias[i];
                        y[i] = f2bf(v > 0.f ? v : 0.f);
                    }
                    *(u16x4*)(o + mt * 16) = y;
                }
            }
        }
        __builtin_amdgcn_sched_barrier(0);
    }
}

// ---------------- fused segment-sum + second GEMM: segments contiguous in Yg
// (dst-order), per-lane divergent sum loop (max-of-16 Poisson(4) ~ 2.3x issue),
// W2 fragments direct from global (131KB L2-resident) -> no staging barriers.
__global__ __launch_bounds__(256) void zgemm_kernel(
    const unsigned short* __restrict__ Yg, const int* __restrict__ rowptrD,
    const unsigned short* __restrict__ W2Tbf, const float* __restrict__ b2,
    unsigned short* __restrict__ msgb, int N)
{
    __shared__ float b2s[512];
    __shared__ int cntS[4 * 64];
    const int tid = threadIdx.x;
    const int w = tid >> 6, lane = tid & 63;
    const int l15 = lane & 15, q = lane >> 4;
    const int nodebase = blockIdx.x * 64 + w * 16;
    const int nA = min(nodebase + l15, N - 1);

    b2s[tid] = b2[tid];
    b2s[tid + 256] = b2[tid + 256];
    const unsigned short* __restrict__ W2l =
        W2Tbf + (size_t)l15 * Hh + q * 8;   // per-lane fragment base

    f32x4 acc[8];
    #pragma unroll
    for (int ct = 0; ct < 8; ct++) acc[ct] = (f32x4){0.f, 0.f, 0.f, 0.f};

    for (int t = 0; t < Tt; t++) {
        const int seg = rowptrD[(size_t)t * N + nA];
        const int len = rowptrD[(size_t)t * N + nA + 1] - seg;
        cntS[w * 64 + t * 16 + l15] = len;

        float asum[32];
        #pragma unroll
        for (int i = 0; i < 32; i++) asum[i] = 0.f;
        for (int j = 0; j < len; j++) {
            const unsigned short* __restrict__ yr = Yg + (size_t)(seg + j) * Hh;
            #pragma unroll
            for (int ks = 0; ks < 4; ks++) {
                u16x8 yv = *(const u16x8*)(yr + ks * 32 + q * 8);
                #pragma unroll
                for (int e = 0; e < 8; e++) asum[ks * 8 + e] += bf2f(yv[e]);
            }
        }

        #pragma unroll
        for (int ks = 0; ks < 4; ks++) {
            u16x8 fr;
            #pragma unroll
            for (int e = 0; e < 8; e++) fr[e] = f2bf(asum[ks * 8 + e]);
            bf16x8 fa = __builtin_bit_cast(bf16x8, fr);
            #pragma unroll
            for (int ct = 0; ct < 8; ct++) {
                bf16x8 fb = *(const bf16x8*)(W2l + ((size_t)t * Hh + ct * 16) * Hh + ks * 32);
                acc[ct] = __builtin_amdgcn_mfma_f32_16x16x32_bf16(fa, fb, acc[ct], 0, 0, 0);
            }
        }
    }
    __syncthreads();   // drain cntS writes before epilogue reads

    #pragma unroll
    for (int ct = 0; ct < 8; ct++) {
        const int c = ct * 16 + l15;
        #pragma unroll
        for (int i = 0; i < 4; i++) {
            int node = nodebase + q * 4 + i;
            if (node < N) {
                float bias = 0.f;
                #pragma unroll
                for (int t = 0; t < Tt; t++)
                    bias += (float)cntS[w * 64 + t * 16 + q * 4 + i] * b2s[t * 128 + c];
                msgb[(size_t)node * Hh + c] = f2bf(acc[ct][i] + bias);
            }
        }
    }
}

// ---------------- GRU: gate-reordered + reg-staged weight prefetch (unchanged)
__global__ __launch_bounds__(512) void gru_kernel(
    const float* __restrict__ h, const unsigned short* __restrict__ h_bf,
    const unsigned short* __restrict__ msgb,
    const unsigned short* __restrict__ wihb, const unsigned short* __restrict__ whhb,
    const float* __restrict__ b_ih, const float* __restrict__ b_hh,
    float* __restrict__ out, int N)
{
    __shared__ unsigned short Wg[128 * WG_LD];
    const int tid = threadIdx.x;
    const int lane = tid & 63;
    const int l15 = lane & 15, q = lane >> 4;
    const int w = tid >> 6;
    const int nodebase = blockIdx.x * 128 + w * 16;
    const int nA = min(nodebase + l15, N - 1);

    bf16x8 fm[4], fh[4];
    #pragma unroll
    for (int ks = 0; ks < 4; ks++) {
        fm[ks] = __builtin_bit_cast(bf16x8, *(const u16x8*)(msgb + (size_t)nA * Hh + ks * 32 + q * 8));
        fh[ks] = __builtin_bit_cast(bf16x8, *(const u16x8*)(h_bf + (size_t)nA * Hh + ks * 32 + q * 8));
    }

    u16x8 pre[4];
    const int so = tid >> 4, sk = (tid & 15) * 8;
    auto loadg = [&](const unsigned short* __restrict__ Ws, int gate) {
        #pragma unroll
        for (int i = 0; i < 4; i++)
            pre[i] = *(const u16x8*)&Ws[(size_t)gate * Hh * Hh + (size_t)(so + i * 32) * Hh + sk];
    };
    auto commit = [&]() {
        __syncthreads();
        #pragma unroll
        for (int i = 0; i < 4; i++)
            *(u16x8*)&Wg[(so + i * 32) * WG_LD + sk] = pre[i];
        __syncthreads();
    };
    auto matmul = [&](f32x4* acc, const bf16x8* fa) {
        #pragma unroll
        for (int ks = 0; ks < 4; ks++) {
            #pragma unroll
            for (int ct = 0; ct < 8; ct++) {
                bf16x8 fb = *(const bf16x8*)&Wg[(ct * 16 + l15) * WG_LD + ks * 32 + q * 8];
                acc[ct] = __builtin_amdgcn_mfma_f32_16x16x32_bf16(fa[ks], fb, acc[ct], 0, 0, 0);
            }
        }
    };

    f32x4 gr[8], gin[8], ghn[8];
    #pragma unroll
    for (int ct = 0; ct < 8; ct++) {
        gr[ct] = (f32x4){0.f, 0.f, 0.f, 0.f};
        gin[ct] = (f32x4){0.f, 0.f, 0.f, 0.f};
        ghn[ct] = (f32x4){0.f, 0.f, 0.f, 0.f};
    }

    loadg(wihb, 0);
    commit(); loadg(whhb, 0); matmul(gr, fm);    // i_r
    commit(); loadg(wihb, 2); matmul(gr, fh);    // + h_r
    commit(); loadg(whhb, 2); matmul(gin, fm);   // i_n
    commit(); loadg(wihb, 1); matmul(ghn, fh);   // h_n

    #pragma unroll
    for (int ct = 0; ct < 8; ct++) {
        const int c = ct * 16 + l15;
        float bir = b_ih[c], bhr = b_hh[c];
        float bin = b_ih[256 + c], bhn = b_hh[256 + c];
        #pragma unroll
        for (int i = 0; i < 4; i++) {
            float rv = 1.f / (1.f + __expf(-(gr[ct][i] + bir + bhr)));
            gin[ct][i] = gin[ct][i] + bin + rv * (ghn[ct][i] + bhn);
        }
    }
    #pragma unroll
    for (int ct = 0; ct < 8; ct++) gr[ct] = (f32x4){0.f, 0.f, 0.f, 0.f};

    commit(); loadg(whhb, 1); matmul(gr, fm);    // i_z
    commit();                 matmul(gr, fh);    // + h_z

    #pragma unroll
    for (int ct = 0; ct < 8; ct++) {
        const int c = ct * 16 + l15;
        float biz = b_ih[128 + c], bhz = b_hh[128 + c];
        #pragma unroll
        for (int i = 0; i < 4; i++) {
            int node = nodebase + q * 4 + i;
            if (node < N) {
                float zv = 1.f / (1.f + __expf(-(gr[ct][i] + biz + bhz)));
                float e2 = __expf(-2.f * gin[ct][i]);
                float nv = (1.f - e2) / (1.f + e2);
                float hv = h[(size_t)node * Hh + c];
                out[(size_t)node * Hh + c] = (1.f - zv) * nv + zv * hv;
            }
        }
    }
}

static inline size_t align256(size_t x) { return (x + 255) & ~(size_t)255; }

extern "C" void kernel_launch(void* const* d_in, const int* in_sizes, int n_in,
                              void* d_out, int out_size, void* d_ws, size_t ws_size,
                              hipStream_t stream)
{
    const float* h     = (const float*)d_in[0];
    const int*   eidx  = (const int*)d_in[1];
    const int*   et    = (const int*)d_in[2];
    const float* eattr = (const float*)d_in[3];
    const float* W1    = (const float*)d_in[4];
    const float* b1    = (const float*)d_in[5];
    const float* W2    = (const float*)d_in[6];
    const float* b2    = (const float*)d_in[7];
    const float* w_ih  = (const float*)d_in[8];
    const float* w_hh  = (const float*)d_in[9];
    const float* b_ih  = (const float*)d_in[10];
    const float* b_hh  = (const float*)d_in[11];

    const int N = in_sizes[0] / Hh;
    const int E = in_sizes[1] / 2;
    const int nb = 4 * N;                       // (type,dst) bins only
    const int sblocks = (nb + 1023) / 1024;     // <= 512 required by scanB

    char* p = (char*)d_ws;
    unsigned short* msgb = (unsigned short*)p; p += align256((size_t)N * Hh * sizeof(unsigned short));
    unsigned short* Yg = (unsigned short*)p;   p += align256((size_t)E * Hh * sizeof(unsigned short));
    int2* rec = (int2*)p;               p += align256((size_t)E * sizeof(int2));
    unsigned* rank = (unsigned*)p;      p += align256((size_t)E * sizeof(unsigned));
    int* rowptrD = (int*)p;             p += align256(((size_t)4 * N + 1) * sizeof(int));
    int* cur = (int*)p;                 p += align256((size_t)nb * sizeof(int));
    int* bsum = (int*)p;                p += align256(1024 * sizeof(int));
    unsigned short* h_bf = (unsigned short*)p; p += align256((size_t)N * Hh * sizeof(unsigned short));
    unsigned short* W1Tbf = (unsigned short*)p; p += align256((size_t)Tt * Hh * K1P * sizeof(unsigned short));
    unsigned short* W2Tbf = (unsigned short*)p; p += align256((size_t)Tt * Hh * Hh * sizeof(unsigned short));
    unsigned short* wihb = (unsigned short*)p; p += align256((size_t)3 * Hh * Hh * sizeof(unsigned short));
    unsigned short* whhb = (unsigned short*)p; p += align256((size_t)3 * Hh * Hh * sizeof(unsigned short));

    hipMemsetAsync(cur, 0, (size_t)nb * sizeof(int), stream);

    {
        int n4h = N * Hh / 4, n4g = 3 * Hh * Hh / 4;
        int c0 = n4h, c1 = c0 + n4g, c2 = c1 + n4g;
        cast_all_kernel<<<(c2 + 255) / 256, 256, 0, stream>>>(
            h, w_ih, w_hh, h_bf, wihb, whhb, c0, c1, c2);
    }
    w1t_kernel<<<Tt * 10, 256, 0, stream>>>(W1, W1Tbf);
    w2t_kernel<<<Tt * 8, 256, 0, stream>>>(W2, W2Tbf);

    hist_kernel<<<1024, 256, 0, stream>>>(et, eidx, E, N, cur, rank);
    scanA_kernel<<<sblocks, 256, 0, stream>>>(cur, nb, bsum);
    scanB_kernel<<<1, 512, 0, stream>>>(bsum, sblocks, rowptrD, 4 * N, E);
    scanC_kernel<<<sblocks, 256, 0, stream>>>(cur, nb, bsum, rowptrD);
    fill2_kernel<<<1024, 256, 0, stream>>>(et, eidx, E, N, cur, rank, rec);

    l1_kernel<<<1024, 512, 0, stream>>>(h_bf, rec, eattr, W1Tbf, b1, rowptrD, Yg, N);
    zgemm_kernel<<<(N + 63) / 64, 256, 0, stream>>>(Yg, rowptrD, W2Tbf, b2, msgb, N);

    int gblocks = (N + 127) / 128;
    gru_kernel<<<gblocks, 512, 0, stream>>>(h, h_bf, msgb, wihb, whhb, b_ih, b_hh, (float*)d_out, N);
}

// Round 8
// 447.521 us; speedup vs baseline: 1.1985x; 1.1985x over previous
//
#include <hip/hip_runtime.h>
#include <stdint.h>

#define Hh 128
#define Aa 16
#define Tt 4
#define K1 144
#define K1P 160     // transposed-weight row length (k 144..159 zeroed)
#define W1T_LD 168  // LDS row stride: 336B -> bank advance 20 dw -> 2-way on fa reads (free)
#define WG_LD  136  // pad: stride 272B -> bank advance 4 dw -> 2-way (free)

typedef float f32x4 __attribute__((ext_vector_type(4)));
typedef __bf16 bf16x8 __attribute__((ext_vector_type(8)));
typedef unsigned short u16x8 __attribute__((ext_vector_type(8)));
typedef unsigned short u16x4 __attribute__((ext_vector_type(4)));

static __device__ __forceinline__ unsigned short f2bf(float f) {
    unsigned u = __builtin_bit_cast(unsigned, f);
    u += 0x7fffu + ((u >> 16) & 1u);   // RNE
    return (unsigned short)(u >> 16);
}

static __device__ __forceinline__ float bf2f(unsigned short u) {
    return __builtin_bit_cast(float, (unsigned)u << 16);
}

static __device__ __forceinline__ bf16x8 pack8(const float* __restrict__ x) {
    f32x4 a = *(const f32x4*)x;
    f32x4 b = *(const f32x4*)(x + 4);
    u16x8 t;
    t[0] = f2bf(a[0]); t[1] = f2bf(a[1]); t[2] = f2bf(a[2]); t[3] = f2bf(a[3]);
    t[4] = f2bf(b[0]); t[5] = f2bf(b[1]); t[6] = f2bf(b[2]); t[7] = f2bf(b[3]);
    return __builtin_bit_cast(bf16x8, t);
}

static __device__ __forceinline__ bf16x8 zero_bf8() {
    u16x8 z = {0, 0, 0, 0, 0, 0, 0, 0};
    return __builtin_bit_cast(bf16x8, z);
}

// ============ fused bf16 pre-cast of h, w_ih, w_hh
__global__ void cast_all_kernel(
    const float* __restrict__ h, const float* __restrict__ wih, const float* __restrict__ whh,
    unsigned short* __restrict__ h_bf, unsigned short* __restrict__ wihb,
    unsigned short* __restrict__ whhb, int n0, int n1, int n2)
{
    int i = blockIdx.x * blockDim.x + threadIdx.x;
    if (i >= n2) return;
    const float* s; unsigned short* d; int off;
    if (i < n0)      { s = h;   d = h_bf; off = i; }
    else if (i < n1) { s = wih; d = wihb; off = i - n0; }
    else             { s = whh; d = whhb; off = i - n1; }
    f32x4 v = *(const f32x4*)(s + (size_t)off * 4);
    u16x4 o;
    o[0] = f2bf(v[0]); o[1] = f2bf(v[1]); o[2] = f2bf(v[2]); o[3] = f2bf(v[3]);
    *(u16x4*)(d + (size_t)off * 4) = o;
}

// ============ one-time transpose+cast: W1 [T][K1][H] f32 -> W1Tbf [T][H][K1P] bf16.
// k in [K1, K1P) zeroed (MUST be zero: garbage could be NaN, NaN*0=NaN in MFMA).
__global__ void w1t_kernel(const float* __restrict__ W1, unsigned short* __restrict__ W1Tbf) {
    __shared__ float tile[16][129];
    const int b = blockIdx.x;
    const int t = b / 10, kb = b % 10;
    const int k0 = kb * 16;
    const int tid = threadIdx.x;
    for (int e = tid; e < 16 * 128; e += 256) {
        int k = e >> 7, n = e & 127;
        tile[k][n] = (k0 + k < K1) ? W1[((size_t)t * K1 + k0 + k) * Hh + n] : 0.f;
    }
    __syncthreads();
    for (int e = tid; e < 128 * 16; e += 256) {
        int n = e >> 4, kk = e & 15;
        W1Tbf[((size_t)t * Hh + n) * K1P + k0 + kk] = f2bf(tile[kk][n]);
    }
}

// ============ one-time transpose+cast: W2 [T][H][H] f32 -> W2Tbf [T][n][k] bf16
__global__ void w2t_kernel(const float* __restrict__ W2, unsigned short* __restrict__ W2Tbf) {
    __shared__ float tile[16][129];
    const int b = blockIdx.x;
    const int t = b >> 3, kb = b & 7;
    const int k0 = kb * 16;
    const int tid = threadIdx.x;
    for (int e = tid; e < 16 * 128; e += 256) {
        int k = e >> 7, n = e & 127;
        tile[k][n] = W2[((size_t)t * Hh + k0 + k) * Hh + n];
    }
    __syncthreads();
    for (int e = tid; e < 128 * 16; e += 256) {
        int n = e >> 4, kk = e & 15;
        W2Tbf[((size_t)t * Hh + n) * Hh + k0 + kk] = f2bf(tile[kk][n]);
    }
}

// ============ bucketing by (type,dst) only: bins [0,4N)
__global__ void hist_kernel(const int* __restrict__ et, const int* __restrict__ eidx,
                            int E, int N, int* __restrict__ cnt, unsigned* __restrict__ rank) {
    for (int i = blockIdx.x * blockDim.x + threadIdx.x; i < E; i += gridDim.x * blockDim.x) {
        rank[i] = (unsigned)atomicAdd(&cnt[et[i] * N + eidx[E + i]], 1);
    }
}

// per-1024-chunk block sums
__global__ void scanA_kernel(const int* __restrict__ deg2, int nb, int* __restrict__ bsum) {
    __shared__ int red[256];
    const int t = threadIdx.x;
    const int i0 = blockIdx.x * 1024 + t * 4;
    int s = 0;
    #pragma unroll
    for (int j = 0; j < 4; j++) if (i0 + j < nb) s += deg2[i0 + j];
    red[t] = s; __syncthreads();
    for (int d = 128; d > 0; d >>= 1) {
        if (t < d) red[t] += red[t + d];
        __syncthreads();
    }
    if (t == 0) bsum[blockIdx.x] = red[0];
}

// single-block exclusive scan of block sums (nblocks <= 512); closes rowptr
__global__ void scanB_kernel(int* __restrict__ bsum, int nblocks,
                             int* __restrict__ rowptrD, int fourN, int E) {
    __shared__ int ts[512];
    const int t = threadIdx.x;
    int v = (t < nblocks) ? bsum[t] : 0;
    ts[t] = v; __syncthreads();
    for (int d = 1; d < 512; d <<= 1) {
        int x = (t >= d) ? ts[t - d] : 0;
        __syncthreads();
        ts[t] += x;
        __syncthreads();
    }
    if (t < nblocks) bsum[t] = ts[t] - v;
    if (t == 0) rowptrD[fourN] = E;
}

// per-chunk exclusive scan + global offset; rowptrD + bin starts in-place
__global__ void scanC_kernel(int* __restrict__ cur, int nb,
                             const int* __restrict__ bsum, int* __restrict__ rowptrD) {
    __shared__ int ts[256];
    const int t = threadIdx.x;
    const int i0 = blockIdx.x * 1024 + t * 4;
    int v[4];
    #pragma unroll
    for (int j = 0; j < 4; j++) v[j] = (i0 + j < nb) ? cur[i0 + j] : 0;
    int s = v[0] + v[1] + v[2] + v[3];
    ts[t] = s; __syncthreads();
    for (int d = 1; d < 256; d <<= 1) {
        int x = (t >= d) ? ts[t - d] : 0;
        __syncthreads();
        ts[t] += x;
        __syncthreads();
    }
    int run = bsum[blockIdx.x] + ts[t] - s;
    #pragma unroll
    for (int j = 0; j < 4; j++) {
        if (i0 + j < nb) {
            rowptrD[i0 + j] = run;
            cur[i0 + j] = run;
            run += v[j];
        }
    }
}

// atomic-free placement into dst-order: rec[posD] = (src, eidx)
__global__ void fill2_kernel(const int* __restrict__ et, const int* __restrict__ eidx,
                             int E, int N, const int* __restrict__ binstart,
                             const unsigned* __restrict__ rank, int2* __restrict__ rec) {
    for (int i = blockIdx.x * blockDim.x + threadIdx.x; i < E; i += gridDim.x * blockDim.x) {
        int posD = binstart[et[i] * N + eidx[E + i]] + (int)rank[i];
        rec[posD] = make_int2(eidx[i], i);
    }
}

// ---------------- layer 1, dst-order + LDS W1 + direct sequential stores.
// dst-order: Yg row = edge's position -> sequential writes, trivial epilogue
// addressing, fused zgemm reads contiguous segments. h[src] is a random gather
// (12.8MB, L3-resident; hidden by TLP). W1 fragments from LDS (round 6 proved
// global-direct costs ~200cy/MFMA-operand: MfmaUtil 7%). UNPINNED registers
// (rounds 1/3: any min-waves pin spills); round-0 contract: 64 VGPR + 64 AGPR
// -> 4 waves/SIMD, 2 blocks/CU. sched_barrier fences stop cross-tile hoisting
// (round 5: pipelining inflated arch VGPR to 128 -> 192 total -> 1 blk/CU).
__global__ __launch_bounds__(512) void l1_kernel(
    const unsigned short* __restrict__ h_bf, const int2* __restrict__ rec,
    const float* __restrict__ eattr, const unsigned short* __restrict__ W1Tbf,
    const float* __restrict__ b1, const int* __restrict__ rowptrD,
    unsigned short* __restrict__ Yg, int N)
{
    __shared__ unsigned short W1T[128 * W1T_LD];
    __shared__ float b1s[128];
    const int t = blockIdx.x & 3;
    const int lb = blockIdx.x >> 2;
    const int nbk = gridDim.x >> 2;
    const int tid = threadIdx.x;

    // staging: coalesced u16x8 copy from pre-transposed W1Tbf (R2: ~1.4M conflicts, free-ish)
    for (int idx = tid; idx < (Hh * K1P) / 8; idx += 512) {
        int n = idx / 20, c = (idx % 20) * 8;
        *(u16x8*)&W1T[n * W1T_LD + c] =
            *(const u16x8*)&W1Tbf[((size_t)t * Hh + n) * K1P + c];
    }
    if (tid < 128) b1s[tid] = b1[t * Hh + tid];
    __syncthreads();

    const int tstart = rowptrD[t * N];
    const int tend = rowptrD[(t + 1) * N];
    const int cnt = tend - tstart;
    const int ntiles = (cnt + 255) >> 8;       // 256 edges per block-tile
    const int w = tid >> 6, lane = tid & 63;
    const int l15 = lane & 15, q = lane >> 4;
    const int tl = tend - 1;

    for (int tile = lb; tile < ntiles; tile += nbk) {
        __builtin_amdgcn_sched_barrier(0);
        const int p0 = tstart + tile * 256 + w * 32;
        const int pa = p0 + l15, pb = p0 + 16 + l15;
        const bool va = pa < tend, vb = pb < tend;
        const int2 ra = rec[min(pa, tl)];
        const int2 rb = rec[min(pb, tl)];
        const unsigned short* __restrict__ hA = h_bf + (size_t)ra.x * Hh;
        const unsigned short* __restrict__ hB = h_bf + (size_t)rb.x * Hh;

        f32x4 acc[8][2];
        #pragma unroll
        for (int mt = 0; mt < 8; mt++) {
            acc[mt][0] = (f32x4){0.f, 0.f, 0.f, 0.f};
            acc[mt][1] = (f32x4){0.f, 0.f, 0.f, 0.f};
        }

        #pragma unroll
        for (int ks = 0; ks < 5; ks++) {
            const int k0 = ks * 32;
            bf16x8 fb_a, fb_b;
            if (ks < 4) {
                fb_a = __builtin_bit_cast(bf16x8, *(const u16x8*)(hA + k0 + q * 8));
                fb_b = __builtin_bit_cast(bf16x8, *(const u16x8*)(hB + k0 + q * 8));
            } else if (q < 2) {
                fb_a = pack8(eattr + (size_t)ra.y * Aa + q * 8);
                fb_b = pack8(eattr + (size_t)rb.y * Aa + q * 8);
            } else {
                fb_a = zero_bf8();
                fb_b = zero_bf8();
            }
            #pragma unroll
            for (int mt = 0; mt < 8; mt++) {
                bf16x8 fa = *(const bf16x8*)&W1T[(mt * 16 + l15) * W1T_LD + k0 + q * 8];
                acc[mt][0] = __builtin_amdgcn_mfma_f32_16x16x32_bf16(fa, fb_a, acc[mt][0], 0, 0, 0);
                acc[mt][1] = __builtin_amdgcn_mfma_f32_16x16x32_bf16(fa, fb_b, acc[mt][1], 0, 0, 0);
            }
        }
        __builtin_amdgcn_sched_barrier(0);

        // epilogue: bias+relu+cvt, SEQUENTIAL rows (pa/pb consecutive in Yg)
        #pragma unroll
        for (int g = 0; g < 2; g++) {
            if (g ? vb : va) {
                unsigned short* __restrict__ o = Yg + (size_t)(g ? pb : pa) * Hh + q * 4;
                #pragma unroll
                for (int mt = 0; mt < 8; mt++) {
                    f32x4 bias = *(const f32x4*)&b1s[mt * 16 + q * 4];
                    u16x4 y;
                    #pragma unroll
                    for (int i = 0; i < 4; i++) {
                        float v = acc[mt][g][i] + bias[i];
                        y[i] = f2bf(v > 0.f ? v : 0.f);
                    }
                    *(u16x4*)(o + mt * 16) = y;
                }
            }
        }
        __builtin_amdgcn_sched_barrier(0);
    }
}

// ---------------- fused segment-sum + second GEMM: segments contiguous in Yg
// (dst-order). Divergence cost: mean len = E/(4N) = 1, wave runs max over 16
// lanes (~3-4) -- hidden by occupancy. W2 staged to LDS (round 6's global-fb
// put ~200cy on every MFMA B-operand); coalesced u16x8 from pre-transposed W2Tbf.
__global__ __launch_bounds__(256) void zgemm_kernel(
    const unsigned short* __restrict__ Yg, const int* __restrict__ rowptrD,
    const unsigned short* __restrict__ W2Tbf, const float* __restrict__ b2,
    unsigned short* __restrict__ msgb, int N)
{
    __shared__ unsigned short W2T[128 * WG_LD];
    __shared__ float b2s[512];
    __shared__ int cntS[4 * 64];
    const int tid = threadIdx.x;
    const int w = tid >> 6, lane = tid & 63;
    const int l15 = lane & 15, q = lane >> 4;
    const int nodebase = blockIdx.x * 64 + w * 16;
    const int nA = min(nodebase + l15, N - 1);

    b2s[tid] = b2[tid];
    b2s[tid + 256] = b2[tid + 256];

    f32x4 acc[8];
    #pragma unroll
    for (int ct = 0; ct < 8; ct++) acc[ct] = (f32x4){0.f, 0.f, 0.f, 0.f};

    for (int t = 0; t < Tt; t++) {
        __syncthreads();
        for (int idx = tid; idx < (Hh * Hh) / 8; idx += 256) {
            int n = idx >> 4, c = (idx & 15) * 8;
            *(u16x8*)&W2T[n * WG_LD + c] =
                *(const u16x8*)&W2Tbf[((size_t)t * Hh + n) * Hh + c];
        }
        __syncthreads();

        const int seg = rowptrD[(size_t)t * N + nA];
        const int len = rowptrD[(size_t)t * N + nA + 1] - seg;
        cntS[w * 64 + t * 16 + l15] = len;

        float asum[32];
        #pragma unroll
        for (int i = 0; i < 32; i++) asum[i] = 0.f;
        for (int j = 0; j < len; j++) {
            const unsigned short* __restrict__ yr = Yg + (size_t)(seg + j) * Hh;
            #pragma unroll
            for (int ks = 0; ks < 4; ks++) {
                u16x8 yv = *(const u16x8*)(yr + ks * 32 + q * 8);
                #pragma unroll
                for (int e = 0; e < 8; e++) asum[ks * 8 + e] += bf2f(yv[e]);
            }
        }

        #pragma unroll
        for (int ks = 0; ks < 4; ks++) {
            u16x8 fr;
            #pragma unroll
            for (int e = 0; e < 8; e++) fr[e] = f2bf(asum[ks * 8 + e]);
            bf16x8 fa = __builtin_bit_cast(bf16x8, fr);
            #pragma unroll
            for (int ct = 0; ct < 8; ct++) {
                bf16x8 fb = *(const bf16x8*)&W2T[(ct * 16 + l15) * WG_LD + ks * 32 + q * 8];
                acc[ct] = __builtin_amdgcn_mfma_f32_16x16x32_bf16(fa, fb, acc[ct], 0, 0, 0);
            }
        }
    }
    __syncthreads();   // drain cntS writes before epilogue reads

    #pragma unroll
    for (int ct = 0; ct < 8; ct++) {
        const int c = ct * 16 + l15;
        #pragma unroll
        for (int i = 0; i < 4; i++) {
            int node = nodebase + q * 4 + i;
            if (node < N) {
                float bias = 0.f;
                #pragma unroll
                for (int t = 0; t < Tt; t++)
                    bias += (float)cntS[w * 64 + t * 16 + q * 4 + i] * b2s[t * 128 + c];
                msgb[(size_t)node * Hh + c] = f2bf(acc[ct][i] + bias);
            }
        }
    }
}

// ---------------- GRU: gate-reordered + reg-staged weight prefetch (unchanged)
__global__ __launch_bounds__(512) void gru_kernel(
    const float* __restrict__ h, const unsigned short* __restrict__ h_bf,
    const unsigned short* __restrict__ msgb,
    const unsigned short* __restrict__ wihb, const unsigned short* __restrict__ whhb,
    const float* __restrict__ b_ih, const float* __restrict__ b_hh,
    float* __restrict__ out, int N)
{
    __shared__ unsigned short Wg[128 * WG_LD];
    const int tid = threadIdx.x;
    const int lane = tid & 63;
    const int l15 = lane & 15, q = lane >> 4;
    const int w = tid >> 6;
    const int nodebase = blockIdx.x * 128 + w * 16;
    const int nA = min(nodebase + l15, N - 1);

    bf16x8 fm[4], fh[4];
    #pragma unroll
    for (int ks = 0; ks < 4; ks++) {
        fm[ks] = __builtin_bit_cast(bf16x8, *(const u16x8*)(msgb + (size_t)nA * Hh + ks * 32 + q * 8));
        fh[ks] = __builtin_bit_cast(bf16x8, *(const u16x8*)(h_bf + (size_t)nA * Hh + ks * 32 + q * 8));
    }

    u16x8 pre[4];
    const int so = tid >> 4, sk = (tid & 15) * 8;
    auto loadg = [&](const unsigned short* __restrict__ Ws, int gate) {
        #pragma unroll
        for (int i = 0; i < 4; i++)
            pre[i] = *(const u16x8*)&Ws[(size_t)gate * Hh * Hh + (size_t)(so + i * 32) * Hh + sk];
    };
    auto commit = [&]() {
        __syncthreads();
        #pragma unroll
        for (int i = 0; i < 4; i++)
            *(u16x8*)&Wg[(so + i * 32) * WG_LD + sk] = pre[i];
        __syncthreads();
    };
    auto matmul = [&](f32x4* acc, const bf16x8* fa) {
        #pragma unroll
        for (int ks = 0; ks < 4; ks++) {
            #pragma unroll
            for (int ct = 0; ct < 8; ct++) {
                bf16x8 fb = *(const bf16x8*)&Wg[(ct * 16 + l15) * WG_LD + ks * 32 + q * 8];
                acc[ct] = __builtin_amdgcn_mfma_f32_16x16x32_bf16(fa[ks], fb, acc[ct], 0, 0, 0);
            }
        }
    };

    f32x4 gr[8], gin[8], ghn[8];
    #pragma unroll
    for (int ct = 0; ct < 8; ct++) {
        gr[ct] = (f32x4){0.f, 0.f, 0.f, 0.f};
        gin[ct] = (f32x4){0.f, 0.f, 0.f, 0.f};
        ghn[ct] = (f32x4){0.f, 0.f, 0.f, 0.f};
    }

    loadg(wihb, 0);
    commit(); loadg(whhb, 0); matmul(gr, fm);    // i_r
    commit(); loadg(wihb, 2); matmul(gr, fh);    // + h_r
    commit(); loadg(whhb, 2); matmul(gin, fm);   // i_n
    commit(); loadg(wihb, 1); matmul(ghn, fh);   // h_n

    #pragma unroll
    for (int ct = 0; ct < 8; ct++) {
        const int c = ct * 16 + l15;
        float bir = b_ih[c], bhr = b_hh[c];
        float bin = b_ih[256 + c], bhn = b_hh[256 + c];
        #pragma unroll
        for (int i = 0; i < 4; i++) {
            float rv = 1.f / (1.f + __expf(-(gr[ct][i] + bir + bhr)));
            gin[ct][i] = gin[ct][i] + bin + rv * (ghn[ct][i] + bhn);
        }
    }
    #pragma unroll
    for (int ct = 0; ct < 8; ct++) gr[ct] = (f32x4){0.f, 0.f, 0.f, 0.f};

    commit(); loadg(whhb, 1); matmul(gr, fm);    // i_z
    commit();                 matmul(gr, fh);    // + h_z

    #pragma unroll
    for (int ct = 0; ct < 8; ct++) {
        const int c = ct * 16 + l15;
        float biz = b_ih[128 + c], bhz = b_hh[128 + c];
        #pragma unroll
        for (int i = 0; i < 4; i++) {
            int node = nodebase + q * 4 + i;
            if (node < N) {
                float zv = 1.f / (1.f + __expf(-(gr[ct][i] + biz + bhz)));
                float e2 = __expf(-2.f * gin[ct][i]);
                float nv = (1.f - e2) / (1.f + e2);
                float hv = h[(size_t)node * Hh + c];
                out[(size_t)node * Hh + c] = (1.f - zv) * nv + zv * hv;
            }
        }
    }
}

static inline size_t align256(size_t x) { return (x + 255) & ~(size_t)255; }

extern "C" void kernel_launch(void* const* d_in, const int* in_sizes, int n_in,
                              void* d_out, int out_size, void* d_ws, size_t ws_size,
                              hipStream_t stream)
{
    const float* h     = (const float*)d_in[0];
    const int*   eidx  = (const int*)d_in[1];
    const int*   et    = (const int*)d_in[2];
    const float* eattr = (const float*)d_in[3];
    const float* W1    = (const float*)d_in[4];
    const float* b1    = (const float*)d_in[5];
    const float* W2    = (const float*)d_in[6];
    const float* b2    = (const float*)d_in[7];
    const float* w_ih  = (const float*)d_in[8];
    const float* w_hh  = (const float*)d_in[9];
    const float* b_ih  = (const float*)d_in[10];
    const float* b_hh  = (const float*)d_in[11];

    const int N = in_sizes[0] / Hh;
    const int E = in_sizes[1] / 2;
    const int nb = 4 * N;                       // (type,dst) bins only
    const int sblocks = (nb + 1023) / 1024;     // <= 512 required by scanB

    char* p = (char*)d_ws;
    unsigned short* msgb = (unsigned short*)p; p += align256((size_t)N * Hh * sizeof(unsigned short));
    unsigned short* Yg = (unsigned short*)p;   p += align256((size_t)E * Hh * sizeof(unsigned short));
    int2* rec = (int2*)p;               p += align256((size_t)E * sizeof(int2));
    unsigned* rank = (unsigned*)p;      p += align256((size_t)E * sizeof(unsigned));
    int* rowptrD = (int*)p;             p += align256(((size_t)4 * N + 1) * sizeof(int));
    int* cur = (int*)p;                 p += align256((size_t)nb * sizeof(int));
    int* bsum = (int*)p;                p += align256(1024 * sizeof(int));
    unsigned short* h_bf = (unsigned short*)p; p += align256((size_t)N * Hh * sizeof(unsigned short));
    unsigned short* W1Tbf = (unsigned short*)p; p += align256((size_t)Tt * Hh * K1P * sizeof(unsigned short));
    unsigned short* W2Tbf = (unsigned short*)p; p += align256((size_t)Tt * Hh * Hh * sizeof(unsigned short));
    unsigned short* wihb = (unsigned short*)p; p += align256((size_t)3 * Hh * Hh * sizeof(unsigned short));
    unsigned short* whhb = (unsigned short*)p; p += align256((size_t)3 * Hh * Hh * sizeof(unsigned short));

    hipMemsetAsync(cur, 0, (size_t)nb * sizeof(int), stream);

    {
        int n4h = N * Hh / 4, n4g = 3 * Hh * Hh / 4;
        int c0 = n4h, c1 = c0 + n4g, c2 = c1 + n4g;
        cast_all_kernel<<<(c2 + 255) / 256, 256, 0, stream>>>(
            h, w_ih, w_hh, h_bf, wihb, whhb, c0, c1, c2);
    }
    w1t_kernel<<<Tt * 10, 256, 0, stream>>>(W1, W1Tbf);
    w2t_kernel<<<Tt * 8, 256, 0, stream>>>(W2, W2Tbf);

    hist_kernel<<<1024, 256, 0, stream>>>(et, eidx, E, N, cur, rank);
    scanA_kernel<<<sblocks, 256, 0, stream>>>(cur, nb, bsum);
    scanB_kernel<<<1, 512, 0, stream>>>(bsum, sblocks, rowptrD, 4 * N, E);
    scanC_kernel<<<sblocks, 256, 0, stream>>>(cur, nb, bsum, rowptrD);
    fill2_kernel<<<1024, 256, 0, stream>>>(et, eidx, E, N, cur, rank, rec);

    l1_kernel<<<2048, 512, 0, stream>>>(h_bf, rec, eattr, W1Tbf, b1, rowptrD, Yg, N);
    zgemm_kernel<<<(N + 63) / 64, 256, 0, stream>>>(Yg, rowptrD, W2Tbf, b2, msgb, N);

    int gblocks = (N + 127) / 128;
    gru_kernel<<<gblocks, 512, 0, stream>>>(h, h_bf, msgb, wihb, whhb, b_ih, b_hh, (float*)d_out, N);
}

// Round 9
// 432.687 us; speedup vs baseline: 1.2395x; 1.0343x over previous
//
#include <hip/hip_runtime.h>
#include <stdint.h>

#define Hh 128
#define Aa 16
#define Tt 4
#define K1 144
#define K1P 160     // transposed-weight row length (k 144..159 zeroed)
#define W1T_LD 168  // LDS row stride: 336B -> bank advance 20 dw -> 2-way on fa reads (free)
#define WG_LD  136  // pad: stride 272B -> bank advance 4 dw -> 2-way (free)

typedef float f32x4 __attribute__((ext_vector_type(4)));
typedef __bf16 bf16x8 __attribute__((ext_vector_type(8)));
typedef unsigned short u16x8 __attribute__((ext_vector_type(8)));
typedef unsigned short u16x4 __attribute__((ext_vector_type(4)));

static __device__ __forceinline__ unsigned short f2bf(float f) {
    unsigned u = __builtin_bit_cast(unsigned, f);
    u += 0x7fffu + ((u >> 16) & 1u);   // RNE
    return (unsigned short)(u >> 16);
}

static __device__ __forceinline__ float bf2f(unsigned short u) {
    return __builtin_bit_cast(float, (unsigned)u << 16);
}

static __device__ __forceinline__ bf16x8 zero_bf8() {
    u16x8 z = {0, 0, 0, 0, 0, 0, 0, 0};
    return __builtin_bit_cast(bf16x8, z);
}

// ============ fused bf16 pre-cast of h, eattr, w_ih, w_hh
// eattr pre-cast moves the f32->bf16 pack off l1's critical path and halves
// the random-gather row size (64B -> 32B).
__global__ void cast_all_kernel(
    const float* __restrict__ h, const float* __restrict__ ea,
    const float* __restrict__ wih, const float* __restrict__ whh,
    unsigned short* __restrict__ h_bf, unsigned short* __restrict__ ebf,
    unsigned short* __restrict__ wihb, unsigned short* __restrict__ whhb,
    int n0, int n1, int n2, int n3)
{
    int i = blockIdx.x * blockDim.x + threadIdx.x;
    if (i >= n3) return;
    const float* s; unsigned short* d; int off;
    if (i < n0)      { s = h;   d = h_bf; off = i; }
    else if (i < n1) { s = ea;  d = ebf;  off = i - n0; }
    else if (i < n2) { s = wih; d = wihb; off = i - n1; }
    else             { s = whh; d = whhb; off = i - n2; }
    f32x4 v = *(const f32x4*)(s + (size_t)off * 4);
    u16x4 o;
    o[0] = f2bf(v[0]); o[1] = f2bf(v[1]); o[2] = f2bf(v[2]); o[3] = f2bf(v[3]);
    *(u16x4*)(d + (size_t)off * 4) = o;
}

// ============ one-time transpose+cast: W1 [T][K1][H] f32 -> W1Tbf [T][H][K1P] bf16.
// k in [K1, K1P) zeroed (MUST be zero: garbage could be NaN, NaN*0=NaN in MFMA).
__global__ void w1t_kernel(const float* __restrict__ W1, unsigned short* __restrict__ W1Tbf) {
    __shared__ float tile[16][129];
    const int b = blockIdx.x;
    const int t = b / 10, kb = b % 10;
    const int k0 = kb * 16;
    const int tid = threadIdx.x;
    for (int e = tid; e < 16 * 128; e += 256) {
        int k = e >> 7, n = e & 127;
        tile[k][n] = (k0 + k < K1) ? W1[((size_t)t * K1 + k0 + k) * Hh + n] : 0.f;
    }
    __syncthreads();
    for (int e = tid; e < 128 * 16; e += 256) {
        int n = e >> 4, kk = e & 15;
        W1Tbf[((size_t)t * Hh + n) * K1P + k0 + kk] = f2bf(tile[kk][n]);
    }
}

// ============ one-time transpose+cast: W2 [T][H][H] f32 -> W2Tbf [T][n][k] bf16
__global__ void w2t_kernel(const float* __restrict__ W2, unsigned short* __restrict__ W2Tbf) {
    __shared__ float tile[16][129];
    const int b = blockIdx.x;
    const int t = b >> 3, kb = b & 7;
    const int k0 = kb * 16;
    const int tid = threadIdx.x;
    for (int e = tid; e < 16 * 128; e += 256) {
        int k = e >> 7, n = e & 127;
        tile[k][n] = W2[((size_t)t * Hh + k0 + k) * Hh + n];
    }
    __syncthreads();
    for (int e = tid; e < 128 * 16; e += 256) {
        int n = e >> 4, kk = e & 15;
        W2Tbf[((size_t)t * Hh + n) * Hh + k0 + kk] = f2bf(tile[kk][n]);
    }
}

// ============ bucketing by (type,dst) only: bins [0,4N)
__global__ void hist_kernel(const int* __restrict__ et, const int* __restrict__ eidx,
                            int E, int N, int* __restrict__ cnt, unsigned* __restrict__ rank) {
    for (int i = blockIdx.x * blockDim.x + threadIdx.x; i < E; i += gridDim.x * blockDim.x) {
        rank[i] = (unsigned)atomicAdd(&cnt[et[i] * N + eidx[E + i]], 1);
    }
}

// per-1024-chunk block sums
__global__ void scanA_kernel(const int* __restrict__ deg2, int nb, int* __restrict__ bsum) {
    __shared__ int red[256];
    const int t = threadIdx.x;
    const int i0 = blockIdx.x * 1024 + t * 4;
    int s = 0;
    #pragma unroll
    for (int j = 0; j < 4; j++) if (i0 + j < nb) s += deg2[i0 + j];
    red[t] = s; __syncthreads();
    for (int d = 128; d > 0; d >>= 1) {
        if (t < d) red[t] += red[t + d];
        __syncthreads();
    }
    if (t == 0) bsum[blockIdx.x] = red[0];
}

// single-block exclusive scan of block sums (nblocks <= 512); closes rowptr
__global__ void scanB_kernel(int* __restrict__ bsum, int nblocks,
                             int* __restrict__ rowptrD, int fourN, int E) {
    __shared__ int ts[512];
    const int t = threadIdx.x;
    int v = (t < nblocks) ? bsum[t] : 0;
    ts[t] = v; __syncthreads();
    for (int d = 1; d < 512; d <<= 1) {
        int x = (t >= d) ? ts[t - d] : 0;
        __syncthreads();
        ts[t] += x;
        __syncthreads();
    }
    if (t < nblocks) bsum[t] = ts[t] - v;
    if (t == 0) rowptrD[fourN] = E;
}

// per-chunk exclusive scan + global offset; rowptrD + bin starts in-place
__global__ void scanC_kernel(int* __restrict__ cur, int nb,
                             const int* __restrict__ bsum, int* __restrict__ rowptrD) {
    __shared__ int ts[256];
    const int t = threadIdx.x;
    const int i0 = blockIdx.x * 1024 + t * 4;
    int v[4];
    #pragma unroll
    for (int j = 0; j < 4; j++) v[j] = (i0 + j < nb) ? cur[i0 + j] : 0;
    int s = v[0] + v[1] + v[2] + v[3];
    ts[t] = s; __syncthreads();
    for (int d = 1; d < 256; d <<= 1) {
        int x = (t >= d) ? ts[t - d] : 0;
        __syncthreads();
        ts[t] += x;
        __syncthreads();
    }
    int run = bsum[blockIdx.x] + ts[t] - s;
    #pragma unroll
    for (int j = 0; j < 4; j++) {
        if (i0 + j < nb) {
            rowptrD[i0 + j] = run;
            cur[i0 + j] = run;
            run += v[j];
        }
    }
}

// atomic-free placement into dst-order: rec[posD] = (src, eidx)
__global__ void fill2_kernel(const int* __restrict__ et, const int* __restrict__ eidx,
                             int E, int N, const int* __restrict__ binstart,
                             const unsigned* __restrict__ rank, int2* __restrict__ rec) {
    for (int i = blockIdx.x * blockDim.x + threadIdx.x; i < E; i += gridDim.x * blockDim.x) {
        int posD = binstart[et[i] * N + eidx[E + i]] + (int)rank[i];
        rec[posD] = make_int2(eidx[i], i);
    }
}

// ---------------- layer 1, dst-order, EXACT-TILE launch: one 256-edge tile per
// block (grid = ceil-total-tiles); block decodes (type, tile) from rowptrD with
// 4 uniform scalar loads. R8 showed occupancy 35.8% vs the 50% reg-cap: grid
// 2048 gave 1.53 ragged generations per type (~35% tail). 3130 one-shot blocks
// = 6.1 generations -> ~16% tail. No tile loop -> no sched_barrier fences.
// Straight-line body keeps the R8-verified 64 VGPR + 64 AGPR contract
// (UNPINNED: R1/R3/R5 proved min-waves pins and forced pipelining both spill).
__global__ __launch_bounds__(512) void l1_kernel(
    const unsigned short* __restrict__ h_bf, const int2* __restrict__ rec,
    const unsigned short* __restrict__ ebf, const unsigned short* __restrict__ W1Tbf,
    const float* __restrict__ b1, const int* __restrict__ rowptrD,
    unsigned short* __restrict__ Yg, int N)
{
    __shared__ unsigned short W1T[128 * W1T_LD];
    __shared__ float b1s[128];
    const int tid = threadIdx.x;

    // uniform decode: (t, tile) from blockIdx
    int rem = blockIdx.x, t = 0, tstart = 0, tend = 0;
    for (; t < Tt; t++) {
        tstart = rowptrD[t * N];
        tend = rowptrD[(t + 1) * N];
        int ntt = (tend - tstart + 255) >> 8;
        if (rem < ntt) break;
        rem -= ntt;
    }
    if (t == Tt) return;   // surplus block (uniform exit, before any barrier)

    // staging: coalesced u16x8 copy from pre-transposed W1Tbf
    for (int idx = tid; idx < (Hh * K1P) / 8; idx += 512) {
        int n = idx / 20, c = (idx % 20) * 8;
        *(u16x8*)&W1T[n * W1T_LD + c] =
            *(const u16x8*)&W1Tbf[((size_t)t * Hh + n) * K1P + c];
    }
    if (tid < 128) b1s[tid] = b1[t * Hh + tid];
    __syncthreads();

    const int w = tid >> 6, lane = tid & 63;
    const int l15 = lane & 15, q = lane >> 4;
    const int tl = tend - 1;

    const int p0 = tstart + rem * 256 + w * 32;
    const int pa = p0 + l15, pb = p0 + 16 + l15;
    const bool va = pa < tend, vb = pb < tend;
    const int2 ra = rec[min(pa, tl)];
    const int2 rb = rec[min(pb, tl)];
    const unsigned short* __restrict__ hA = h_bf + (size_t)ra.x * Hh;
    const unsigned short* __restrict__ hB = h_bf + (size_t)rb.x * Hh;

    f32x4 acc[8][2];
    #pragma unroll
    for (int mt = 0; mt < 8; mt++) {
        acc[mt][0] = (f32x4){0.f, 0.f, 0.f, 0.f};
        acc[mt][1] = (f32x4){0.f, 0.f, 0.f, 0.f};
    }

    #pragma unroll
    for (int ks = 0; ks < 5; ks++) {
        const int k0 = ks * 32;
        bf16x8 fb_a, fb_b;
        if (ks < 4) {
            fb_a = __builtin_bit_cast(bf16x8, *(const u16x8*)(hA + k0 + q * 8));
            fb_b = __builtin_bit_cast(bf16x8, *(const u16x8*)(hB + k0 + q * 8));
        } else if (q < 2) {
            fb_a = __builtin_bit_cast(bf16x8, *(const u16x8*)(ebf + (size_t)ra.y * Aa + q * 8));
            fb_b = __builtin_bit_cast(bf16x8, *(const u16x8*)(ebf + (size_t)rb.y * Aa + q * 8));
        } else {
            fb_a = zero_bf8();
            fb_b = zero_bf8();
        }
        #pragma unroll
        for (int mt = 0; mt < 8; mt++) {
            bf16x8 fa = *(const bf16x8*)&W1T[(mt * 16 + l15) * W1T_LD + k0 + q * 8];
            acc[mt][0] = __builtin_amdgcn_mfma_f32_16x16x32_bf16(fa, fb_a, acc[mt][0], 0, 0, 0);
            acc[mt][1] = __builtin_amdgcn_mfma_f32_16x16x32_bf16(fa, fb_b, acc[mt][1], 0, 0, 0);
        }
    }

    // epilogue: bias+relu+cvt, SEQUENTIAL rows (pa/pb consecutive in Yg)
    #pragma unroll
    for (int g = 0; g < 2; g++) {
        if (g ? vb : va) {
            unsigned short* __restrict__ o = Yg + (size_t)(g ? pb : pa) * Hh + q * 4;
            #pragma unroll
            for (int mt = 0; mt < 8; mt++) {
                f32x4 bias = *(const f32x4*)&b1s[mt * 16 + q * 4];
                u16x4 y;
                #pragma unroll
                for (int i = 0; i < 4; i++) {
                    float v = acc[mt][g][i] + bias[i];
                    y[i] = f2bf(v > 0.f ? v : 0.f);
                }
                *(u16x4*)(o + mt * 16) = y;
            }
        }
    }
}

// ---------------- fused segment-sum + second GEMM: segments contiguous in Yg
// (dst-order). Mean len = E/(4N) = 4; wave runs max over its lanes (~9-13) --
// memory-bound on the contiguous Yg read, hidden by occupancy. W2 staged to LDS.
__global__ __launch_bounds__(256) void zgemm_kernel(
    const unsigned short* __restrict__ Yg, const int* __restrict__ rowptrD,
    const unsigned short* __restrict__ W2Tbf, const float* __restrict__ b2,
    unsigned short* __restrict__ msgb, int N)
{
    __shared__ unsigned short W2T[128 * WG_LD];
    __shared__ float b2s[512];
    __shared__ int cntS[4 * 64];
    const int tid = threadIdx.x;
    const int w = tid >> 6, lane = tid & 63;
    const int l15 = lane & 15, q = lane >> 4;
    const int nodebase = blockIdx.x * 64 + w * 16;
    const int nA = min(nodebase + l15, N - 1);

    b2s[tid] = b2[tid];
    b2s[tid + 256] = b2[tid + 256];

    f32x4 acc[8];
    #pragma unroll
    for (int ct = 0; ct < 8; ct++) acc[ct] = (f32x4){0.f, 0.f, 0.f, 0.f};

    for (int t = 0; t < Tt; t++) {
        __syncthreads();
        for (int idx = tid; idx < (Hh * Hh) / 8; idx += 256) {
            int n = idx >> 4, c = (idx & 15) * 8;
            *(u16x8*)&W2T[n * WG_LD + c] =
                *(const u16x8*)&W2Tbf[((size_t)t * Hh + n) * Hh + c];
        }
        __syncthreads();

        const int seg = rowptrD[(size_t)t * N + nA];
        const int len = rowptrD[(size_t)t * N + nA + 1] - seg;
        cntS[w * 64 + t * 16 + l15] = len;

        float asum[32];
        #pragma unroll
        for (int i = 0; i < 32; i++) asum[i] = 0.f;
        for (int j = 0; j < len; j++) {
            const unsigned short* __restrict__ yr = Yg + (size_t)(seg + j) * Hh;
            #pragma unroll
            for (int ks = 0; ks < 4; ks++) {
                u16x8 yv = *(const u16x8*)(yr + ks * 32 + q * 8);
                #pragma unroll
                for (int e = 0; e < 8; e++) asum[ks * 8 + e] += bf2f(yv[e]);
            }
        }

        #pragma unroll
        for (int ks = 0; ks < 4; ks++) {
            u16x8 fr;
            #pragma unroll
            for (int e = 0; e < 8; e++) fr[e] = f2bf(asum[ks * 8 + e]);
            bf16x8 fa = __builtin_bit_cast(bf16x8, fr);
            #pragma unroll
            for (int ct = 0; ct < 8; ct++) {
                bf16x8 fb = *(const bf16x8*)&W2T[(ct * 16 + l15) * WG_LD + ks * 32 + q * 8];
                acc[ct] = __builtin_amdgcn_mfma_f32_16x16x32_bf16(fa, fb, acc[ct], 0, 0, 0);
            }
        }
    }
    __syncthreads();   // drain cntS writes before epilogue reads

    #pragma unroll
    for (int ct = 0; ct < 8; ct++) {
        const int c = ct * 16 + l15;
        #pragma unroll
        for (int i = 0; i < 4; i++) {
            int node = nodebase + q * 4 + i;
            if (node < N) {
                float bias = 0.f;
                #pragma unroll
                for (int t = 0; t < Tt; t++)
                    bias += (float)cntS[w * 64 + t * 16 + q * 4 + i] * b2s[t * 128 + c];
                msgb[(size_t)node * Hh + c] = f2bf(acc[ct][i] + bias);
            }
        }
    }
}

// ---------------- GRU: gate-reordered + reg-staged weight prefetch (unchanged)
__global__ __launch_bounds__(512) void gru_kernel(
    const float* __restrict__ h, const unsigned short* __restrict__ h_bf,
    const unsigned short* __restrict__ msgb,
    const unsigned short* __restrict__ wihb, const unsigned short* __restrict__ whhb,
    const float* __restrict__ b_ih, const float* __restrict__ b_hh,
    float* __restrict__ out, int N)
{
    __shared__ unsigned short Wg[128 * WG_LD];
    const int tid = threadIdx.x;
    const int lane = tid & 63;
    const int l15 = lane & 15, q = lane >> 4;
    const int w = tid >> 6;
    const int nodebase = blockIdx.x * 128 + w * 16;
    const int nA = min(nodebase + l15, N - 1);

    bf16x8 fm[4], fh[4];
    #pragma unroll
    for (int ks = 0; ks < 4; ks++) {
        fm[ks] = __builtin_bit_cast(bf16x8, *(const u16x8*)(msgb + (size_t)nA * Hh + ks * 32 + q * 8));
        fh[ks] = __builtin_bit_cast(bf16x8, *(const u16x8*)(h_bf + (size_t)nA * Hh + ks * 32 + q * 8));
    }

    u16x8 pre[4];
    const int so = tid >> 4, sk = (tid & 15) * 8;
    auto loadg = [&](const unsigned short* __restrict__ Ws, int gate) {
        #pragma unroll
        for (int i = 0; i < 4; i++)
            pre[i] = *(const u16x8*)&Ws[(size_t)gate * Hh * Hh + (size_t)(so + i * 32) * Hh + sk];
    };
    auto commit = [&]() {
        __syncthreads();
        #pragma unroll
        for (int i = 0; i < 4; i++)
            *(u16x8*)&Wg[(so + i * 32) * WG_LD + sk] = pre[i];
        __syncthreads();
    };
    auto matmul = [&](f32x4* acc, const bf16x8* fa) {
        #pragma unroll
        for (int ks = 0; ks < 4; ks++) {
            #pragma unroll
            for (int ct = 0; ct < 8; ct++) {
                bf16x8 fb = *(const bf16x8*)&Wg[(ct * 16 + l15) * WG_LD + ks * 32 + q * 8];
                acc[ct] = __builtin_amdgcn_mfma_f32_16x16x32_bf16(fa[ks], fb, acc[ct], 0, 0, 0);
            }
        }
    };

    f32x4 gr[8], gin[8], ghn[8];
    #pragma unroll
    for (int ct = 0; ct < 8; ct++) {
        gr[ct] = (f32x4){0.f, 0.f, 0.f, 0.f};
        gin[ct] = (f32x4){0.f, 0.f, 0.f, 0.f};
        ghn[ct] = (f32x4){0.f, 0.f, 0.f, 0.f};
    }

    loadg(wihb, 0);
    commit(); loadg(whhb, 0); matmul(gr, fm);    // i_r
    commit(); loadg(wihb, 2); matmul(gr, fh);    // + h_r
    commit(); loadg(whhb, 2); matmul(gin, fm);   // i_n
    commit(); loadg(wihb, 1); matmul(ghn, fh);   // h_n

    #pragma unroll
    for (int ct = 0; ct < 8; ct++) {
        const int c = ct * 16 + l15;
        float bir = b_ih[c], bhr = b_hh[c];
        float bin = b_ih[256 + c], bhn = b_hh[256 + c];
        #pragma unroll
        for (int i = 0; i < 4; i++) {
            float rv = 1.f / (1.f + __expf(-(gr[ct][i] + bir + bhr)));
            gin[ct][i] = gin[ct][i] + bin + rv * (ghn[ct][i] + bhn);
        }
    }
    #pragma unroll
    for (int ct = 0; ct < 8; ct++) gr[ct] = (f32x4){0.f, 0.f, 0.f, 0.f};

    commit(); loadg(whhb, 1); matmul(gr, fm);    // i_z
    commit();                 matmul(gr, fh);    // + h_z

    #pragma unroll
    for (int ct = 0; ct < 8; ct++) {
        const int c = ct * 16 + l15;
        float biz = b_ih[128 + c], bhz = b_hh[128 + c];
        #pragma unroll
        for (int i = 0; i < 4; i++) {
            int node = nodebase + q * 4 + i;
            if (node < N) {
                float zv = 1.f / (1.f + __expf(-(gr[ct][i] + biz + bhz)));
                float e2 = __expf(-2.f * gin[ct][i]);
                float nv = (1.f - e2) / (1.f + e2);
                float hv = h[(size_t)node * Hh + c];
                out[(size_t)node * Hh + c] = (1.f - zv) * nv + zv * hv;
            }
        }
    }
}

static inline size_t align256(size_t x) { return (x + 255) & ~(size_t)255; }

extern "C" void kernel_launch(void* const* d_in, const int* in_sizes, int n_in,
                              void* d_out, int out_size, void* d_ws, size_t ws_size,
                              hipStream_t stream)
{
    const float* h     = (const float*)d_in[0];
    const int*   eidx  = (const int*)d_in[1];
    const int*   et    = (const int*)d_in[2];
    const float* eattr = (const float*)d_in[3];
    const float* W1    = (const float*)d_in[4];
    const float* b1    = (const float*)d_in[5];
    const float* W2    = (const float*)d_in[6];
    const float* b2    = (const float*)d_in[7];
    const float* w_ih  = (const float*)d_in[8];
    const float* w_hh  = (const float*)d_in[9];
    const float* b_ih  = (const float*)d_in[10];
    const float* b_hh  = (const float*)d_in[11];

    const int N = in_sizes[0] / Hh;
    const int E = in_sizes[1] / 2;
    const int nb = 4 * N;                       // (type,dst) bins only
    const int sblocks = (nb + 1023) / 1024;     // <= 512 required by scanB

    char* p = (char*)d_ws;
    unsigned short* msgb = (unsigned short*)p; p += align256((size_t)N * Hh * sizeof(unsigned short));
    unsigned short* Yg = (unsigned short*)p;   p += align256((size_t)E * Hh * sizeof(unsigned short));
    int2* rec = (int2*)p;               p += align256((size_t)E * sizeof(int2));
    unsigned* rank = (unsigned*)p;      p += align256((size_t)E * sizeof(unsigned));
    int* rowptrD = (int*)p;             p += align256(((size_t)4 * N + 1) * sizeof(int));
    int* cur = (int*)p;                 p += align256((size_t)nb * sizeof(int));
    int* bsum = (int*)p;                p += align256(1024 * sizeof(int));
    unsigned short* h_bf = (unsigned short*)p; p += align256((size_t)N * Hh * sizeof(unsigned short));
    unsigned short* ebf = (unsigned short*)p;  p += align256((size_t)E * Aa * sizeof(unsigned short));
    unsigned short* W1Tbf = (unsigned short*)p; p += align256((size_t)Tt * Hh * K1P * sizeof(unsigned short));
    unsigned short* W2Tbf = (unsigned short*)p; p += align256((size_t)Tt * Hh * Hh * sizeof(unsigned short));
    unsigned short* wihb = (unsigned short*)p; p += align256((size_t)3 * Hh * Hh * sizeof(unsigned short));
    unsigned short* whhb = (unsigned short*)p; p += align256((size_t)3 * Hh * Hh * sizeof(unsigned short));

    hipMemsetAsync(cur, 0, (size_t)nb * sizeof(int), stream);

    {
        int n4h = N * Hh / 4, n4e = E * Aa / 4, n4g = 3 * Hh * Hh / 4;
        int c0 = n4h, c1 = c0 + n4e, c2 = c1 + n4g, c3 = c2 + n4g;
        cast_all_kernel<<<(c3 + 255) / 256, 256, 0, stream>>>(
            h, eattr, w_ih, w_hh, h_bf, ebf, wihb, whhb, c0, c1, c2, c3);
    }
    w1t_kernel<<<Tt * 10, 256, 0, stream>>>(W1, W1Tbf);
    w2t_kernel<<<Tt * 8, 256, 0, stream>>>(W2, W2Tbf);

    hist_kernel<<<1024, 256, 0, stream>>>(et, eidx, E, N, cur, rank);
    scanA_kernel<<<sblocks, 256, 0, stream>>>(cur, nb, bsum);
    scanB_kernel<<<1, 512, 0, stream>>>(bsum, sblocks, rowptrD, 4 * N, E);
    scanC_kernel<<<sblocks, 256, 0, stream>>>(cur, nb, bsum, rowptrD);
    fill2_kernel<<<1024, 256, 0, stream>>>(et, eidx, E, N, cur, rank, rec);

    // exact-tile launch: one 256-edge tile per block (+Tt for per-type ceil slack)
    int l1grid = E / 256 + Tt + 1;
    l1_kernel<<<l1grid, 512, 0, stream>>>(h_bf, rec, ebf, W1Tbf, b1, rowptrD, Yg, N);
    zgemm_kernel<<<(N + 63) / 64, 256, 0, stream>>>(Yg, rowptrD, W2Tbf, b2, msgb, N);

    int gblocks = (N + 127) / 128;
    gru_kernel<<<gblocks, 512, 0, stream>>>(h, h_bf, msgb, wihb, whhb, b_ih, b_hh, (float*)d_out, N);
}